// Round 15
// baseline (63.039 us; speedup 1.0000x reference)
//
#include <hip/hip_runtime.h>
#include <hip/hip_bf16.h>

// RoIAlign forward, torchvision semantics (aligned=false), fp32 in/out.
// N=2, C=256, H=200, W=200, K=1000 rois, pooled 7x7, sampling_ratio=2.
// Model (R1-R13): scattered-gather request-path bound (~14 B/cy/CU delivered,
// saturating in wave-concurrency). R15 (=R14 with compile fix): final
// concurrency step - bf16 LDS stage (13.6KB) + launch_bounds(256,8) ->
// 8 blocks/CU = 32 waves (100% cap). bf16 pack via manual RTNE bit trick
// (this ROCm's __hip_bfloat16 has no public .data).
constexpr int Nn = 2, Cc = 256, Hh = 200, Ww = 200, Kk = 1000;
constexpr int PH = 7, PW = 7, SR = 2;
constexpr float SCALE = 0.25f;
constexpr int HWsz = Hh * Ww;
constexpr int NXCD = 8;
constexpr unsigned NUNITS = 2 * Kk;             // (roi, half) pairs
constexpr unsigned CHUNK = NUNITS / NXCD;       // 250
constexpr int SLD = 53;  // stage row stride (ushorts): 106B -> 2-way banks

// ---------------------------------------------------------------------------
// NCHW fp32 -> NHWC bf16 (RTNE). 64x64 LDS tiles, coalesced both sides.
// ---------------------------------------------------------------------------
__global__ __launch_bounds__(256) void transpose_to_nhwc_bf16(
    const float* __restrict__ in, __hip_bfloat16* __restrict__ out) {
  __shared__ float tile[64][65];
  const int hw0 = blockIdx.x * 64;
  const int c0  = blockIdx.y * 64;
  const int b   = blockIdx.z;
  const int lane = threadIdx.x & 63;
  const int row  = threadIdx.x >> 6;  // 0..3

#pragma unroll
  for (int i = 0; i < 16; ++i) {
    const int cc = row + i * 4;
    tile[cc][lane] = in[(size_t)(b * Cc + c0 + cc) * HWsz + hw0 + lane];
  }
  __syncthreads();
#pragma unroll
  for (int i = 0; i < 16; ++i) {
    const int hh = row + i * 4;
    out[((size_t)b * HWsz + hw0 + hh) * Cc + c0 + lane] =
        __float2bfloat16(tile[lane][hh]);
  }
}

// ---------------------------------------------------------------------------
// Morton-order counting sort of rois by (batch, morton(yc/8, xc/8)).
// 2048 buckets; single-pass (K=1000 <= 1024 threads); Hillis-Steele scan.
// Per-roi output location fixed by roi index -> order nondeterminism harmless.
// ---------------------------------------------------------------------------
__global__ __launch_bounds__(1024) void sort_rois(
    const float* __restrict__ rois, unsigned* __restrict__ order) {
  __shared__ unsigned A[2048], B[2048];
  const int tid = (int)threadIdx.x;
  A[tid] = 0; A[tid + 1024] = 0;
  __syncthreads();

  unsigned kk = 0;
  const bool act = tid < Kk;
  if (act) {
    const float* r = rois + tid * 5;
    int yc = (int)(0.5f * (r[2] + r[4]) * SCALE);
    int xc = (int)(0.5f * (r[1] + r[3]) * SCALE);
    yc = yc < 0 ? 0 : (yc > 199 ? 199 : yc);
    xc = xc < 0 ? 0 : (xc > 199 ? 199 : xc);
    const unsigned ty = (unsigned)yc >> 3, tx = (unsigned)xc >> 3;  // 0..24
    unsigned m = 0;
#pragma unroll
    for (int i = 0; i < 5; ++i)
      m |= (((ty >> i) & 1u) << (2 * i + 1)) | (((tx >> i) & 1u) << (2 * i));
    kk = (unsigned)r[0] * 1024u + m;
    atomicAdd(&A[kk], 1u);
  }
  __syncthreads();

  unsigned* src = A;
  unsigned* dst = B;
  for (int d = 1; d < 2048; d <<= 1) {
    for (int j = tid; j < 2048; j += 1024) {
      unsigned v = src[j];
      if (j >= d) v += src[j - d];
      dst[j] = v;
    }
    __syncthreads();
    unsigned* t = src; src = dst; dst = t;
  }
  for (int j = tid; j < 2048; j += 1024) dst[j] = j ? src[j - 1] : 0u;
  __syncthreads();

  if (act) {
    const unsigned pos = atomicAdd(&dst[kk], 1u);
    order[pos] = (unsigned)tid;
  }
}

// Manual RTNE f32 -> bf16 (same rounding as __float2bfloat16 for non-NaN).
__device__ __forceinline__ ushort f2bf(float v) {
  unsigned u = __float_as_uint(v);
  u += 0x7fffu + ((u >> 16) & 1u);
  return (ushort)(u >> 16);
}

// ---------------------------------------------------------------------------
// RoI align on NHWC bf16, XCD-chunked over Morton-sorted units.
// Block = 256 threads (4 waves); unit -> (roi = order[u>>1], half = u&1).
// Wave w handles bins p in [ceil(49w/4), ceil(49(w+1)/4)) (13/12/12/12).
// Lane: ixl = lane>>5 (x-sample column), cq = lane&31 (channel quad of the
// 128-ch half; ushort4 = 8B loads -> 2x256B coalesced segments per gather).
// Results staged as bf16 in LDS [128][53] (13.6KB -> 8 blocks/CU, 32 waves);
// one barrier; coalesced f32 NT write-out (full-line dirtying, R12 lesson).
// ---------------------------------------------------------------------------
__global__ __launch_bounds__(256, 8) void roi_align_hiocc(
    const ushort* __restrict__ feat, const float* __restrict__ rois,
    const unsigned* __restrict__ order, float* __restrict__ out) {
  __shared__ ushort stage[128 * SLD];  // bf16 stage, 13568 B

  const unsigned bid = blockIdx.x;
  const unsigned unit = (bid % NXCD) * CHUNK + bid / NXCD;

  const int tid  = (int)threadIdx.x;
  const int w    = tid >> 6;        // wave 0..3
  const int lane = tid & 63;
  const int ixl  = lane >> 5;       // sample column parity
  const int cq   = lane & 31;       // channel quad in half

  const int k    = (int)order[unit >> 1];
  const int half = (int)(unit & 1);

  const float* r = rois + k * 5;
  const int b = (int)r[0];
  const float x1 = r[1] * SCALE;
  const float y1 = r[2] * SCALE;
  const float x2 = r[3] * SCALE;
  const float y2 = r[4] * SCALE;
  const float bin_w = fmaxf(x2 - x1, 1.0f) * (1.0f / PW);
  const float bin_h = fmaxf(y2 - y1, 1.0f) * (1.0f / PH);

  // ushort4 view; per-(y,x) stride is 64 quads; this lane's channel quad.
  const ushort4* fb =
      (const ushort4*)(feat + (size_t)b * HWsz * Cc) + half * 32 + cq;

  auto bf2f = [](ushort u) -> float {
    return __uint_as_float((unsigned)u << 16);
  };
  const float x_off = ((float)ixl + 0.5f) * 0.5f;  // per-lane sample offset
  const float inv = 1.0f / (SR * SR);

  const int p0 = (49 * w + 3) >> 2;        // {0,13,25,37}
  const int p1 = (49 * (w + 1) + 3) >> 2;  // {13,25,37,49}

  for (int p = p0; p < p1; ++p) {
    const int ph = p / 7;
    const int pw = p - ph * 7;

    // x setup (per-lane sample column).
    const float x  = x1 + ((float)pw + x_off) * bin_w;
    const bool vx  = (x >= -1.0f) && (x <= (float)Ww);
    const float cx = fmaxf(x, 0.0f);
    int xl = (int)cx;
    int xh;
    float fx;
    if (xl >= Ww - 1) { xl = Ww - 1; xh = Ww - 1; fx = 0.0f; }
    else              { xh = xl + 1; fx = cx - (float)xl; }
    float wxl = 1.0f - fx, wxh = fx;
    if (!vx) { wxl = 0.0f; wxh = 0.0f; }

    float4 a = make_float4(0.f, 0.f, 0.f, 0.f);

#pragma unroll
    for (int iy = 0; iy < SR; ++iy) {
      const float y  = y1 + ((float)ph + ((float)iy + 0.5f) * 0.5f) * bin_h;
      const bool vy  = (y >= -1.0f) && (y <= (float)Hh);
      const float cy = fmaxf(y, 0.0f);
      int yl = (int)cy;  // cy >= 0: trunc == floor
      int yh;
      float fy;
      if (yl >= Hh - 1) { yl = Hh - 1; yh = Hh - 1; fy = 0.0f; }
      else              { yh = yl + 1; fy = cy - (float)yl; }
      float wyl = 1.0f - fy, wyh = fy;
      if (!vy) { wyl = 0.0f; wyh = 0.0f; }

      const float w00 = wyl * wxl, w01 = wyl * wxh;
      const float w10 = wyh * wxl, w11 = wyh * wxh;

      const ushort4 v00 = fb[(yl * Ww + xl) * 64];
      const ushort4 v01 = fb[(yl * Ww + xh) * 64];
      const ushort4 v10 = fb[(yh * Ww + xl) * 64];
      const ushort4 v11 = fb[(yh * Ww + xh) * 64];

      a.x = fmaf(w00, bf2f(v00.x), fmaf(w01, bf2f(v01.x),
            fmaf(w10, bf2f(v10.x), fmaf(w11, bf2f(v11.x), a.x))));
      a.y = fmaf(w00, bf2f(v00.y), fmaf(w01, bf2f(v01.y),
            fmaf(w10, bf2f(v10.y), fmaf(w11, bf2f(v11.y), a.y))));
      a.z = fmaf(w00, bf2f(v00.z), fmaf(w01, bf2f(v01.z),
            fmaf(w10, bf2f(v10.z), fmaf(w11, bf2f(v11.z), a.z))));
      a.w = fmaf(w00, bf2f(v00.w), fmaf(w01, bf2f(v01.w),
            fmaf(w10, bf2f(v10.w), fmaf(w11, bf2f(v11.w), a.w))));
    }

    // Fold the two x-sample columns: lane L <-> lane L^32.
    a.x += __shfl_xor(a.x, 32);
    a.y += __shfl_xor(a.y, 32);
    a.z += __shfl_xor(a.z, 32);
    a.w += __shfl_xor(a.w, 32);

    if (lane < 32) {
      const int c0 = cq * 4;
      // bf16 stage (RTNE); row stride 53 ushorts = 106B -> 2-way banks (free)
      stage[(c0 + 0) * SLD + p] = f2bf(a.x * inv);
      stage[(c0 + 1) * SLD + p] = f2bf(a.y * inv);
      stage[(c0 + 2) * SLD + p] = f2bf(a.z * inv);
      stage[(c0 + 3) * SLD + p] = f2bf(a.w * inv);
    }
  }
  __syncthreads();  // stage complete (each wave wrote its own bins)

  const size_t obase =
      (size_t)k * (Cc * PH * PW) + (size_t)half * (128 * PH * PW);
  // 128*49 = 6272 floats = 24.5 x 256 threads; coalesced f32 NT stores.
#pragma unroll
  for (int i = 0; i < 24; ++i) {
    const int idx = i * 256 + tid;
    const int c = idx / 49, p = idx - c * 49;
    __builtin_nontemporal_store(bf2f(stage[c * SLD + p]), &out[obase + idx]);
  }
  {
    const int idx = 24 * 256 + tid;
    if (idx < 6272) {
      const int c = idx / 49, p = idx - c * 49;
      __builtin_nontemporal_store(bf2f(stage[c * SLD + p]), &out[obase + idx]);
    }
  }
}

extern "C" void kernel_launch(void* const* d_in, const int* in_sizes, int n_in,
                              void* d_out, int out_size, void* d_ws, size_t ws_size,
                              hipStream_t stream) {
  const float* inp  = (const float*)d_in[0];   // (2,256,200,200) fp32
  const float* rois = (const float*)d_in[1];   // (1000,5) fp32
  float* out = (float*)d_out;                  // (1000,256,7,7) fp32

  __hip_bfloat16* nhwc = (__hip_bfloat16*)d_ws;                // 41 MB
  unsigned* order = (unsigned*)((char*)d_ws + (48u << 20));    // 4KB @48MB

  transpose_to_nhwc_bf16<<<dim3(HWsz / 64, Cc / 64, Nn), 256, 0, stream>>>(inp, nhwc);
  sort_rois<<<dim3(1), 1024, 0, stream>>>(rois, order);
  roi_align_hiocc<<<dim3(NUNITS), 256, 0, stream>>>((const ushort*)nhwc, rois, order, out);
}